// Round 12
// baseline (375.920 us; speedup 1.0000x reference)
//
#include <hip/hip_runtime.h>

// ---------------------------------------------------------------------------
// EdgeLLMAttentionTRTNative: out = X @ (s*Wo@Wq)^T + kv_cache passthrough.
// Round 12: hide memory work under the SMALL GEMM via co-resident helper
// blocks (multi-block/CU TLP — the R11 epilogue-fusion failed because the
// 112KB-LDS big GEMM is 1 block/CU and epilogue copies delay round-2).
//   prep : Wq transpose + Wo cast (one launch).
//   mega : 192 helper blocks (X-cast 150MB + kv copy 268MB) + 576 m97-style
//          128-tile GEMM blocks (16KB LDS -> 3+ blocks/CU co-resident).
//   gemm5: R5-verified big GEMM (BM=256 BN=192 BK=64, 4-phase, vmcnt(3),
//          chunk-XOR swizzle), no epilogue.
// ---------------------------------------------------------------------------

typedef __attribute__((ext_vector_type(8))) __bf16 bf16x8;
typedef __attribute__((ext_vector_type(4))) float f32x4;

__device__ __forceinline__ unsigned short f2bf(float f) {
  union { float f; unsigned u; } v; v.f = f;
  unsigned r = v.u + 0x7fffu + ((v.u >> 16) & 1u);   // round-to-nearest-even
  return (unsigned short)(r >> 16);
}

__device__ __forceinline__ ushort4 cast4(float4 v) {
  ushort4 o;
  o.x = f2bf(v.x); o.y = f2bf(v.y); o.z = f2bf(v.z); o.w = f2bf(v.w);
  return o;
}

typedef const __attribute__((address_space(1))) void* gptr_t;
typedef __attribute__((address_space(3))) void* lptr_t;

__device__ __forceinline__ void gload16(const void* g, void* l) {
  __builtin_amdgcn_global_load_lds((gptr_t)g, (lptr_t)l, 16, 0, 0);
}

#define BAR   do { asm volatile("" ::: "memory"); __builtin_amdgcn_s_barrier(); asm volatile("" ::: "memory"); } while (0)
#define LGKM0 asm volatile("s_waitcnt lgkmcnt(0)" ::: "memory")
#define VM(n) asm volatile("s_waitcnt vmcnt(" #n ")" ::: "memory")

// ---------------------------------------------------------------------------
// prep: blocks [0,9216) transpose+cast Wq (3072x3072 f32 -> WqT bf16);
//       blocks [9216,10240) cast Wo f32 -> bf16.
// ---------------------------------------------------------------------------
__global__ void prep(const float* __restrict__ Wq, ushort* __restrict__ WqT,
                     const float4* __restrict__ Wo4, ushort4* __restrict__ Wob4) {
  __shared__ float tile[32][33];
  const int H = 3072;
  if (blockIdx.x < 9216) {
    const int id = blockIdx.x;
    const int tc = (id % 96) * 32;
    const int tr = (id / 96) * 32;
    const int lx = threadIdx.x & 31;
    const int ly = threadIdx.x >> 5;
#pragma unroll
    for (int i = 0; i < 32; i += 8)
      tile[ly + i][lx] = Wq[(size_t)(tr + ly + i) * H + (tc + lx)];
    __syncthreads();
#pragma unroll
    for (int i = 0; i < 32; i += 8)
      WqT[(size_t)(tc + ly + i) * H + (tr + lx)] = f2bf(tile[lx][ly + i]);
  } else {
    const int n4 = (H * H) / 4;                    // 2_359_296
    int i = (blockIdx.x - 9216) * 256 + threadIdx.x;
    for (; i < n4; i += 1024 * 256)
      Wob4[i] = cast4(Wo4[i]);
  }
}

// ---------------------------------------------------------------------------
// mega: blocks [0,192) = helpers (X cast + kv copy, grid-stride);
//       blocks [192,768) = small GEMM W = s * Wo @ Wq  (bf16 out).
// GEMM: m97 structure, 128x128 tile, BK=32, 4 waves, chunk-XOR swizzle
// (verified rounds 3-5). nwg=576 bijective XCD swizzle. 16KB LDS -> multi
// block/CU, so helper memory traffic hides under GEMM compute (TLP).
// ---------------------------------------------------------------------------
__global__ __launch_bounds__(256)
void mega(const ushort* __restrict__ A,     // Wob (3072x3072 bf16)
          const ushort* __restrict__ B,     // WqTb (3072x3072 bf16)
          ushort* __restrict__ Cw,          // Wb out (bf16)
          const float4* __restrict__ hs4, ushort4* __restrict__ Xb4,
          const float4* __restrict__ kvsrc, float4* __restrict__ kvdst,
          float scale) {
  __shared__ __align__(16) ushort As[128 * 32];
  __shared__ __align__(16) ushort Bs[128 * 32];

  const int HH = 3072;
  if (blockIdx.x < 192) {
    // ---- helper: X cast then kv copy (grid-stride over 192*256 threads)
    const int gtid = blockIdx.x * 256 + threadIdx.x;
    const int gstr = 192 * 256;
    const int nx4 = (8192 * HH) / 4;               // 6_291_456
    for (int i = gtid; i < nx4; i += gstr)
      Xb4[i] = cast4(hs4[i]);
    if (kvdst) {
      const int nkv4 = 8388608;
      for (int i = gtid; i < nkv4; i += gstr)
        kvdst[i] = kvsrc[i];
    }
    return;
  }

  const int bid  = blockIdx.x - 192;       // 0..575
  const int t    = threadIdx.x;
  const int w    = t >> 6;
  const int lane = t & 63;
  const int wr   = w >> 1, wc = w & 1;
  const int fr   = lane & 15;
  const int g    = lane >> 4;

  // bijective XCD swizzle over nwg=576 (%8==0)
  const int wg  = (bid & 7) * 72 + (bid >> 3);
  const int nbx = HH >> 7;                 // 24
  const int bx  = wg % nbx, by = wg / nbx;
  const int rowBase = by * 128, colBase = bx * 128;

  const int r0 = t >> 2;
  const int sc = ((t & 3) ^ ((t >> 3) & 3)) << 3;
  const ushort* Ag0 = A + (size_t)(rowBase + r0) * HH + sc;
  const ushort* Ag1 = A + (size_t)(rowBase + 64 + r0) * HH + sc;
  const ushort* Bg0 = B + (size_t)(colBase + r0) * HH + sc;
  const ushort* Bg1 = B + (size_t)(colBase + 64 + r0) * HH + sc;
  ushort* Al0 = &As[w * 512];
  ushort* Al1 = &As[2048 + w * 512];
  ushort* Bl0 = &Bs[w * 512];
  ushort* Bl1 = &Bs[2048 + w * 512];

  const int swz8 = (g ^ ((fr >> 1) & 3)) << 3;

  f32x4 acc[4][4];
#pragma unroll
  for (int m = 0; m < 4; ++m)
#pragma unroll
    for (int n = 0; n < 4; ++n)
      acc[m][n] = f32x4{0.f, 0.f, 0.f, 0.f};

  for (int k0 = 0; k0 < HH; k0 += 32) {
    __syncthreads();
    gload16(Ag0 + k0, Al0);
    gload16(Ag1 + k0, Al1);
    gload16(Bg0 + k0, Bl0);
    gload16(Bg1 + k0, Bl1);
    __syncthreads();

    bf16x8 a[4], b[4];
#pragma unroll
    for (int m = 0; m < 4; ++m)
      a[m] = *(const bf16x8*)&As[(wr * 64 + m * 16 + fr) * 32 + swz8];
#pragma unroll
    for (int n = 0; n < 4; ++n)
      b[n] = *(const bf16x8*)&Bs[(wc * 64 + n * 16 + fr) * 32 + swz8];

#pragma unroll
    for (int m = 0; m < 4; ++m)
#pragma unroll
      for (int n = 0; n < 4; ++n)
        acc[m][n] = __builtin_amdgcn_mfma_f32_16x16x32_bf16(a[m], b[n], acc[m][n], 0, 0, 0);
  }

  const int orow = rowBase + wr * 64 + (g << 2);
  const int ocol = colBase + wc * 64 + fr;
#pragma unroll
  for (int m = 0; m < 4; ++m)
#pragma unroll
    for (int n = 0; n < 4; ++n)
#pragma unroll
      for (int i = 0; i < 4; ++i) {
        const size_t idx = (size_t)(orow + m * 16 + i) * HH + (ocol + n * 16);
        Cw[idx] = f2bf(acc[m][n][i] * scale);
      }
}

// ---------------------------------------------------------------------------
// Big GEMM (round-5 verified): C(f32) = A(MxK)*B(NxK)^T. BM=256 BN=192 BK=64.
// 8 waves 2Mx4N; 2-buffer LDS 112KB; 4 phases/tile; vmcnt(3) ladder;
// chunk-XOR swizzle via pre-swizzled global source.
// ---------------------------------------------------------------------------
__global__ __launch_bounds__(512, 2)
void gemm5(const ushort* __restrict__ A, const ushort* __restrict__ B,
           float* __restrict__ C, int M, int N, int K) {
  __shared__ __align__(16) char smem[114688];

  const int t    = threadIdx.x;
  const int w    = t >> 6;
  const int lane = t & 63;
  const int wr   = w >> 2;
  const int wc   = w & 3;
  const int fr   = lane & 15;
  const int g    = lane >> 4;

  const int nwg = gridDim.x;
  const int cpx = nwg >> 3;
  const int wg  = (blockIdx.x & 7) * cpx + (blockIdx.x >> 3);
  const int nbx = N / 192;
  const int bx  = wg % nbx, by = wg / nbx;
  const int rowBase = by * 256, colBase = bx * 192;

  const int sr   = lane >> 3;
  const int scol = ((lane & 7) ^ sr) << 3;
  const ushort* Ag = A + (size_t)(rowBase + w * 8 + sr) * K + scol;
  const ushort* Bg = B + (size_t)(colBase + w * 8 + sr) * K + scol;
  const int wofs = w * 1024;

#define STAGE_A_LOW(kt)  do { char* d_ = smem + ((kt) & 1) * 57344 + wofs;          \
    const ushort* s_ = Ag + (size_t)(kt) * 64;                                      \
    gload16(s_, d_); gload16(s_ + (size_t)64 * K, d_ + 8192); } while (0)
#define STAGE_A_HIGH(kt) do { char* d_ = smem + ((kt) & 1) * 57344 + 16384 + wofs;  \
    const ushort* s_ = Ag + (size_t)128 * K + (size_t)(kt) * 64;                    \
    gload16(s_, d_); gload16(s_ + (size_t)64 * K, d_ + 8192); } while (0)
#define STAGE_B(kt)      do { char* d_ = smem + ((kt) & 1) * 57344 + 32768 + wofs;  \
    const ushort* s_ = Bg + (size_t)(kt) * 64;                                      \
    gload16(s_, d_); gload16(s_ + (size_t)64 * K, d_ + 8192);                       \
    gload16(s_ + (size_t)128 * K, d_ + 16384); } while (0)

  const int aBase = (wr * 128 + fr) * 128;
  const int bBase = 32768 + (wc * 48 + fr) * 128;
  const int cs0   = (g ^ (fr & 7)) << 4;
  const int cs1   = ((4 | g) ^ (fr & 7)) << 4;

#define READ_A(dst, bo, MH, CS) do {                                  \
    const char* p_ = smem + (bo) + aBase + (MH) * 8192 + (CS);        \
    dst[0] = *(const bf16x8*)(p_);                                    \
    dst[1] = *(const bf16x8*)(p_ + 2048);                             \
    dst[2] = *(const bf16x8*)(p_ + 4096);                             \
    dst[3] = *(const bf16x8*)(p_ + 6144); } while (0)
#define READ_B(dst, bo, CS) do {                                      \
    const char* p_ = smem + (bo) + bBase + (CS);                      \
    dst[0] = *(const bf16x8*)(p_);                                    \
    dst[1] = *(const bf16x8*)(p_ + 2048);                             \
    dst[2] = *(const bf16x8*)(p_ + 4096); } while (0)
#define MFMA_Q(MH, aset, bset) do {                                   \
    _Pragma("unroll") for (int mi_ = 0; mi_ < 4; ++mi_)               \
    _Pragma("unroll") for (int ni_ = 0; ni_ < 3; ++ni_)               \
      acc[(MH) * 4 + mi_][ni_] = __builtin_amdgcn_mfma_f32_16x16x32_bf16( \
          aset[mi_], bset[ni_], acc[(MH) * 4 + mi_][ni_], 0, 0, 0); } while (0)

  f32x4 acc[8][3];
#pragma unroll
  for (int m = 0; m < 8; ++m)
#pragma unroll
    for (int n = 0; n < 3; ++n)
      acc[m][n] = f32x4{0.f, 0.f, 0.f, 0.f};

  bf16x8 aA[4], aB[4], Bk0[3], Bk1[3];

  const int nt = K >> 6;               // 48

  STAGE_A_LOW(0); STAGE_B(0); STAGE_A_HIGH(0);
  STAGE_A_LOW(1); STAGE_B(1); STAGE_A_HIGH(1);
  VM(7);
  BAR;
  READ_A(aA, 0, 0, cs0);
  READ_B(Bk0, 0, cs0);

  for (int T = 0; T < nt; ++T) {
    const int bo  = (T & 1) * 57344;
    const int bon = 57344 - bo;
    const bool stg = (T + 2) < nt;
    // P1
    READ_A(aB, bo, 0, cs1);
    READ_B(Bk1, bo, cs1);
    BAR; LGKM0;
    __builtin_amdgcn_s_setprio(1); MFMA_Q(0, aA, Bk0); __builtin_amdgcn_s_setprio(0);
    BAR;
    // P2
    READ_A(aA, bo, 1, cs0);
    BAR; LGKM0;
    __builtin_amdgcn_s_setprio(1); MFMA_Q(0, aB, Bk1); __builtin_amdgcn_s_setprio(0);
    BAR;
    // P3
    if (stg) STAGE_B(T + 2);
    READ_A(aB, bo, 1, cs1);
    BAR; LGKM0;
    __builtin_amdgcn_s_setprio(1); MFMA_Q(1, aA, Bk0); __builtin_amdgcn_s_setprio(0);
    if (T < nt - 2) { VM(3); } else { VM(0); }
    BAR;
    // P4
    if (stg) { STAGE_A_LOW(T + 2); STAGE_A_HIGH(T + 2); }
    if (T + 1 < nt) { READ_A(aA, bon, 0, cs0); READ_B(Bk0, bon, cs0); }
    BAR; LGKM0;
    __builtin_amdgcn_s_setprio(1); MFMA_Q(1, aB, Bk1); __builtin_amdgcn_s_setprio(0);
    BAR;
  }

#undef STAGE_A_LOW
#undef STAGE_A_HIGH
#undef STAGE_B
#undef READ_A
#undef READ_B
#undef MFMA_Q

  const int orow = rowBase + wr * 128 + (g << 2);
  const int ocol = colBase + wc * 48 + fr;
#pragma unroll
  for (int mi = 0; mi < 8; ++mi)
#pragma unroll
    for (int ni = 0; ni < 3; ++ni)
#pragma unroll
      for (int i = 0; i < 4; ++i)
        C[(size_t)(orow + mi * 16 + i) * N + (ocol + ni * 16)] = acc[mi][ni][i];
}

extern "C" void kernel_launch(void* const* d_in, const int* in_sizes, int n_in,
                              void* d_out, int out_size, void* d_ws, size_t ws_size,
                              hipStream_t stream) {
  const float* hs = (const float*)d_in[0];   // (4,2048,3072)
  const float* kv = (const float*)d_in[4];   // (4,2,8,4096,128)
  const float* Wq = (const float*)d_in[5];   // (3072,3072) (d,h)
  const float* Wo = (const float*)d_in[8];   // (3072,3072) (o,d)

  const int M = 8192, H = 3072;
  const int OUT_ELEMS = M * H;
  const int nkv = in_sizes[4];               // 33_554_432 floats

  float* out = (float*)d_out;

  // Workspace (bf16): Xb 48MB, Wob 18MB, WqTb 18MB, Wb 18MB (if it fits).
  ushort* Xb   = (ushort*)d_ws;
  ushort* Wob  = Xb + (size_t)M * H;
  ushort* WqTb = Wob + (size_t)H * H;
  const size_t WS_NEED = 2ull * ((size_t)M * H + 3ull * (size_t)H * H);
  const bool ws_ok = ws_size >= WS_NEED;
  ushort* Wb = ws_ok ? (WqTb + (size_t)H * H) : (ushort*)(out + OUT_ELEMS);

  const float qk_scale = 0.08838834764831845f;  // 128^-0.5

  // 1) Wq transpose-cast + Wo cast (one launch).
  prep<<<10240, 256, 0, stream>>>(Wq, WqTb, (const float4*)Wo, (ushort4*)Wob);

  // 2) mega: helpers (X cast + kv copy) co-resident with small GEMM.
  const float4* kvs = ws_ok ? (const float4*)kv : nullptr;
  float4* kvd = ws_ok ? (float4*)(out + OUT_ELEMS) : nullptr;
  mega<<<768, 256, 0, stream>>>(Wob, WqTb, Wb, (const float4*)hs,
                                (ushort4*)Xb, kvs, kvd, qk_scale);

  // 3) big GEMM: out = X @ W^T (grid 32*16 = 512, %8==0).
  gemm5<<<(M / 256) * (H / 192), 512, 0, stream>>>(Xb, Wb, out, M, H, H);

  if (!ws_ok) {
    hipMemcpyAsync(out + OUT_ELEMS, kv, (size_t)nkv * sizeof(float),
                   hipMemcpyDeviceToDevice, stream);
  }
}

// Round 13
// 320.961 us; speedup vs baseline: 1.1712x; 1.1712x over previous
//
#include <hip/hip_runtime.h>

// ---------------------------------------------------------------------------
// EdgeLLMAttentionTRTNative: out = X @ (s*Wo@Wq)^T + kv_cache passthrough.
// Round 13: 2-blocks/CU exact-fill GEMM. BM=128 BN=192 BK=64, 8 waves
// (2Mx4N, per-wave 64x48), LDS 2x40KB = 81920B = exactly half a CU ->
// 2 blocks/CU. Big grid 1024 = 2/CU x 256 x 2 rounds exactly; small grid
// 384 = 1 round. Stage(T+1) at phase 1 gives the end-of-tile vmcnt(0) a
// full tile of latency cover; co-resident block hides the rest. R5's
// verified chunk-XOR swizzle. Prep fused to one launch; serial kv memcpy.
// ---------------------------------------------------------------------------

typedef __attribute__((ext_vector_type(8))) __bf16 bf16x8;
typedef __attribute__((ext_vector_type(4))) float f32x4;

__device__ __forceinline__ unsigned short f2bf(float f) {
  union { float f; unsigned u; } v; v.f = f;
  unsigned r = v.u + 0x7fffu + ((v.u >> 16) & 1u);   // round-to-nearest-even
  return (unsigned short)(r >> 16);
}

__device__ __forceinline__ ushort4 cast4(float4 v) {
  ushort4 o;
  o.x = f2bf(v.x); o.y = f2bf(v.y); o.z = f2bf(v.z); o.w = f2bf(v.w);
  return o;
}

typedef const __attribute__((address_space(1))) void* gptr_t;
typedef __attribute__((address_space(3))) void* lptr_t;

__device__ __forceinline__ void gload16(const void* g, void* l) {
  __builtin_amdgcn_global_load_lds((gptr_t)g, (lptr_t)l, 16, 0, 0);
}

#define BAR   do { asm volatile("" ::: "memory"); __builtin_amdgcn_s_barrier(); asm volatile("" ::: "memory"); } while (0)
#define LGKM0 asm volatile("s_waitcnt lgkmcnt(0)" ::: "memory")
#define VM(n) asm volatile("s_waitcnt vmcnt(" #n ")" ::: "memory")

// ---------------------------------------------------------------------------
// prep_all: [0,2048) X cast; [2048,11264) Wq 32x32 transpose-cast tiles;
// [11264,12288) Wo cast. One launch replaces three.
// ---------------------------------------------------------------------------
__global__ __launch_bounds__(256)
void prep_all(const float4* __restrict__ hs4, ushort4* __restrict__ Xb4,
              const float* __restrict__ Wq, ushort* __restrict__ WqT,
              const float4* __restrict__ Wo4, ushort4* __restrict__ Wob4) {
  __shared__ float tile[32][33];
  const int H = 3072;
  const int b = blockIdx.x;
  if (b < 2048) {
    const int nx4 = 6291456;                       // 8192*3072/4
    for (int i = b * 256 + threadIdx.x; i < nx4; i += 2048 * 256)
      Xb4[i] = cast4(hs4[i]);
  } else if (b < 11264) {
    const int id = b - 2048;                       // 0..9215 (96x96 tiles)
    const int tc = (id % 96) * 32;
    const int tr = (id / 96) * 32;
    const int lx = threadIdx.x & 31;
    const int ly = threadIdx.x >> 5;
#pragma unroll
    for (int i = 0; i < 32; i += 8)
      tile[ly + i][lx] = Wq[(size_t)(tr + ly + i) * H + (tc + lx)];
    __syncthreads();
#pragma unroll
    for (int i = 0; i < 32; i += 8)
      WqT[(size_t)(tc + ly + i) * H + (tr + lx)] = f2bf(tile[lx][ly + i]);
  } else {
    const int nw4 = 2359296;                       // 3072*3072/4
    for (int i = (b - 11264) * 256 + threadIdx.x; i < nw4; i += 1024 * 256)
      Wob4[i] = cast4(Wo4[i]);
  }
}

// ---------------------------------------------------------------------------
// GEMM: C = A(rows x K) * B(cols x K)^T. BM=128 BN=192 BK=64.
// 8 waves 2Mx4N; per-wave 64x48 -> acc[4][3] (48 AGPR).
// LDS slot: A 128x64 (16KB) + B 192x64 (24KB) = 40KB; x2 = 81920B
// (exactly half of 160KB -> 2 blocks/CU; __launch_bounds__(512,4)).
// Swizzle (R5-verified): 16B chunk c of row r stored at c^(r&7) via
// pre-swizzled global source; frag rows have row&7 == fr&7 (48,64,16 all
// multiples of 8), staging rows have row&7 == lane>>3.
// Schedule per tile T (slot s=T&1):
//   Ph1: read kh0 frags (7 b128, slot s); STAGE(T+1 -> s^1, 5 gloads);
//        LGKM0; 12 MFMA.
//   Ph2: read kh1 frags (7 b128); LGKM0; 12 MFMA; VM(0); BAR.
// The stage->use gap is one full tile (~900cy) so VM(0) is mostly covered;
// the co-resident block (2/CU) hides the rest. Reads of s^1 from tile T-1
// drained by its Ph2 LGKM0 before its barrier -> stage is race-free.
// ---------------------------------------------------------------------------
template <int OUT_BF16>
__global__ __launch_bounds__(512, 4)
void gemm_n(const ushort* __restrict__ A, const ushort* __restrict__ B,
            void* __restrict__ Cv, int N, int K, float scale) {
  __shared__ __align__(16) char smem[81920];

  const int t    = threadIdx.x;
  const int w    = t >> 6;
  const int lane = t & 63;
  const int wr   = w >> 2;             // 0..1 (M: 64 rows each)
  const int wc   = w & 3;              // 0..3 (N: 48 cols each)
  const int fr   = lane & 15;
  const int g    = lane >> 4;          // 0..3

  // XCD-aware bijective swizzle: nwg % 8 == 0 (1024 / 384).
  const int nwg = gridDim.x;
  const int cpx = nwg >> 3;
  const int wg  = (blockIdx.x & 7) * cpx + (blockIdx.x >> 3);
  const int nbx = N / 192;
  const int bx  = wg % nbx, by = wg / nbx;
  const int rowBase = by * 128, colBase = bx * 192;

  // Staging: per 8KB region = 64 rows x 128B; wave w rows [w*8,w*8+8);
  // lane l row +(l>>3), stored chunk l&7 = logical (l&7)^(l>>3).
  const int sr   = lane >> 3;
  const int scol = ((lane & 7) ^ sr) << 3;
  const ushort* Ag = A + (size_t)(rowBase + w * 8 + sr) * K + scol;
  const ushort* Bg = B + (size_t)(colBase + w * 8 + sr) * K + scol;
  const int wofs = w << 10;            // per-wave LDS dest offset

#define SLOT(T) (((T) & 1) * 40960)
// A: 2 regions (rows 0-63, 64-127); B: 3 regions. 5 gloads/thread/tile.
#define STAGE(kt) do {                                                  \
    char* d_ = smem + SLOT(kt) + wofs;                                  \
    const ushort* sa_ = Ag + (size_t)(kt) * 64;                         \
    gload16(sa_, d_);                                                   \
    gload16(sa_ + (size_t)64 * K, d_ + 8192);                           \
    const ushort* sb_ = Bg + (size_t)(kt) * 64;                         \
    gload16(sb_,                    d_ + 16384);                        \
    gload16(sb_ + (size_t)64 * K,   d_ + 24576);                        \
    gload16(sb_ + (size_t)128 * K,  d_ + 32768); } while (0)

  // Fragment reads: row stride 128B; logical chunk kh*4+g at XOR (fr&7).
  const int aBase = (wr * 64 + fr) * 128;
  const int bBase = 16384 + (wc * 48 + fr) * 128;
  const int cs0   = (g ^ (fr & 7)) << 4;            // kh=0
  const int cs1   = ((4 | g) ^ (fr & 7)) << 4;      // kh=1

#define READ_A(dst, so, CS) do {                                        \
    const char* p_ = smem + (so) + aBase + (CS);                        \
    dst[0] = *(const bf16x8*)(p_);                                      \
    dst[1] = *(const bf16x8*)(p_ + 2048);                               \
    dst[2] = *(const bf16x8*)(p_ + 4096);                               \
    dst[3] = *(const bf16x8*)(p_ + 6144); } while (0)
#define READ_B(dst, so, CS) do {                                        \
    const char* p_ = smem + (so) + bBase + (CS);                        \
    dst[0] = *(const bf16x8*)(p_);                                      \
    dst[1] = *(const bf16x8*)(p_ + 2048);                               \
    dst[2] = *(const bf16x8*)(p_ + 4096); } while (0)
#define MFMA12(A4, B3) do {                                             \
    _Pragma("unroll") for (int mi_ = 0; mi_ < 4; ++mi_)                 \
    _Pragma("unroll") for (int ni_ = 0; ni_ < 3; ++ni_)                 \
      acc[mi_][ni_] = __builtin_amdgcn_mfma_f32_16x16x32_bf16(          \
          A4[mi_], B3[ni_], acc[mi_][ni_], 0, 0, 0); } while (0)

  f32x4 acc[4][3];
#pragma unroll
  for (int m = 0; m < 4; ++m)
#pragma unroll
    for (int n = 0; n < 3; ++n)
      acc[m][n] = f32x4{0.f, 0.f, 0.f, 0.f};

  bf16x8 Af[4], Bf[3];

  const int nt = K >> 6;               // 48

  STAGE(0);
  VM(0);
  BAR;

  for (int T = 0; T < nt; ++T) {
    const int so = SLOT(T);
    // Ph1: kh0
    READ_A(Af, so, cs0);
    READ_B(Bf, so, cs0);
    if (T + 1 < nt) STAGE(T + 1);      // -> slot so^1 (readers drained T-1)
    LGKM0;
    __builtin_amdgcn_s_setprio(1); MFMA12(Af, Bf); __builtin_amdgcn_s_setprio(0);
    // Ph2: kh1
    READ_A(Af, so, cs1);
    READ_B(Bf, so, cs1);
    LGKM0;
    __builtin_amdgcn_s_setprio(1); MFMA12(Af, Bf); __builtin_amdgcn_s_setprio(0);
    VM(0);                             // tile T+1 landed (issued ~1 tile ago)
    BAR;                               // all waves done reading slot so
  }

#undef STAGE
#undef READ_A
#undef READ_B
#undef MFMA12
#undef SLOT

  // C/D layout: col = lane&15, row = (lane>>4)*4 + i
  const int orow = rowBase + wr * 64 + (g << 2);
  const int ocol = colBase + wc * 48 + fr;
#pragma unroll
  for (int mi = 0; mi < 4; ++mi)
#pragma unroll
    for (int ni = 0; ni < 3; ++ni)
#pragma unroll
      for (int i = 0; i < 4; ++i) {
        const size_t idx = (size_t)(orow + mi * 16 + i) * N + (ocol + ni * 16);
        float v = acc[mi][ni][i] * scale;
        if (OUT_BF16) ((ushort*)Cv)[idx] = f2bf(v);
        else          ((float*)Cv)[idx]  = v;
      }
}

extern "C" void kernel_launch(void* const* d_in, const int* in_sizes, int n_in,
                              void* d_out, int out_size, void* d_ws, size_t ws_size,
                              hipStream_t stream) {
  const float* hs = (const float*)d_in[0];   // (4,2048,3072)
  const float* kv = (const float*)d_in[4];   // (4,2,8,4096,128)
  const float* Wq = (const float*)d_in[5];   // (3072,3072) (d,h)
  const float* Wo = (const float*)d_in[8];   // (3072,3072) (o,d)

  const int M = 8192, H = 3072;
  const int OUT_ELEMS = M * H;
  const int nkv = in_sizes[4];               // 33_554_432 floats

  float* out = (float*)d_out;

  // Workspace (bf16): Xb 48MB, Wob 18MB, WqTb 18MB, Wb 18MB (if it fits).
  ushort* Xb   = (ushort*)d_ws;
  ushort* Wob  = Xb + (size_t)M * H;
  ushort* WqTb = Wob + (size_t)H * H;
  const size_t WS_NEED = 2ull * ((size_t)M * H + 3ull * (size_t)H * H);
  const bool ws_ok = ws_size >= WS_NEED;
  // Wb in ws when possible; else in d_out kv-tail (overwritten by the
  // trailing kv memcpy, stream-ordered).
  ushort* Wb = ws_ok ? (WqTb + (size_t)H * H) : (ushort*)(out + OUT_ELEMS);

  const float qk_scale = 0.08838834764831845f;  // 128^-0.5

  // 1) all prep in one launch.
  prep_all<<<12288, 256, 0, stream>>>((const float4*)hs, (ushort4*)Xb,
                                      Wq, WqTb, (const float4*)Wo,
                                      (ushort4*)Wob);

  // 2) W = s * Wo @ Wq  (grid 24*16 = 384, 1 round at 2 blocks/CU).
  gemm_n<1><<<(H / 128) * (H / 192), 512, 0, stream>>>(
      Wob, WqTb, (void*)Wb, H, H, qk_scale);

  // 3) out = X @ W^T  (grid 64*16 = 1024 = 2/CU x 256 CUs x 2 rounds exact).
  gemm_n<0><<<(M / 128) * (H / 192), 512, 0, stream>>>(
      Xb, Wb, (void*)out, H, H, 1.0f);

  // 4) kv passthrough (also overwrites Wb scratch in the !ws_ok path).
  hipMemcpyAsync(out + OUT_ELEMS, kv, (size_t)nkv * sizeof(float),
                 hipMemcpyDeviceToDevice, stream);
}

// Round 14
// 318.067 us; speedup vs baseline: 1.1819x; 1.0091x over previous
//
#include <hip/hip_runtime.h>

// ---------------------------------------------------------------------------
// EdgeLLMAttentionTRTNative: out = X @ (s*Wo@Wq)^T + kv_cache passthrough.
// Round 14: R13 structure (2 blocks/CU, 1 barrier/tile, vmcnt(0) covered by
// one-tile stage->use gap + co-resident block) with the wave geometry fixed
// for LDS/MFMA balance: per-wave 64x96 (ratio ab/(a+b)=2.4, was 1.71).
// BM=128 BN=192 BK=64, 4 waves (256 thr, 2Mx2N), acc[4][6]; LDS 2x40KB =
// 81920B -> 2 blocks/CU (163840B = exactly 160KiB, proven fit in R13).
// Per CU-step: LDS 1920 cyc vs MFMA 1862 cyc (R13: 2688 vs 1862).
// Grids: big 64x16=1024 = 2 exact rounds; small 24x16=384.
// ---------------------------------------------------------------------------

typedef __attribute__((ext_vector_type(8))) __bf16 bf16x8;
typedef __attribute__((ext_vector_type(4))) float f32x4;

__device__ __forceinline__ unsigned short f2bf(float f) {
  union { float f; unsigned u; } v; v.f = f;
  unsigned r = v.u + 0x7fffu + ((v.u >> 16) & 1u);   // round-to-nearest-even
  return (unsigned short)(r >> 16);
}

__device__ __forceinline__ ushort4 cast4(float4 v) {
  ushort4 o;
  o.x = f2bf(v.x); o.y = f2bf(v.y); o.z = f2bf(v.z); o.w = f2bf(v.w);
  return o;
}

typedef const __attribute__((address_space(1))) void* gptr_t;
typedef __attribute__((address_space(3))) void* lptr_t;

__device__ __forceinline__ void gload16(const void* g, void* l) {
  __builtin_amdgcn_global_load_lds((gptr_t)g, (lptr_t)l, 16, 0, 0);
}

#define BAR   do { asm volatile("" ::: "memory"); __builtin_amdgcn_s_barrier(); asm volatile("" ::: "memory"); } while (0)
#define LGKM0 asm volatile("s_waitcnt lgkmcnt(0)" ::: "memory")
#define VM(n) asm volatile("s_waitcnt vmcnt(" #n ")" ::: "memory")

// ---------------------------------------------------------------------------
// prep_all: [0,2048) X cast; [2048,11264) Wq 32x32 transpose-cast tiles;
// [11264,12288) Wo cast.
// ---------------------------------------------------------------------------
__global__ __launch_bounds__(256)
void prep_all(const float4* __restrict__ hs4, ushort4* __restrict__ Xb4,
              const float* __restrict__ Wq, ushort* __restrict__ WqT,
              const float4* __restrict__ Wo4, ushort4* __restrict__ Wob4) {
  __shared__ float tile[32][33];
  const int H = 3072;
  const int b = blockIdx.x;
  if (b < 2048) {
    const int nx4 = 6291456;                       // 8192*3072/4
    for (int i = b * 256 + threadIdx.x; i < nx4; i += 2048 * 256)
      Xb4[i] = cast4(hs4[i]);
  } else if (b < 11264) {
    const int id = b - 2048;                       // 0..9215 (96x96 tiles)
    const int tc = (id % 96) * 32;
    const int tr = (id / 96) * 32;
    const int lx = threadIdx.x & 31;
    const int ly = threadIdx.x >> 5;
#pragma unroll
    for (int i = 0; i < 32; i += 8)
      tile[ly + i][lx] = Wq[(size_t)(tr + ly + i) * H + (tc + lx)];
    __syncthreads();
#pragma unroll
    for (int i = 0; i < 32; i += 8)
      WqT[(size_t)(tc + ly + i) * H + (tr + lx)] = f2bf(tile[lx][ly + i]);
  } else {
    const int nw4 = 2359296;                       // 3072*3072/4
    for (int i = (b - 11264) * 256 + threadIdx.x; i < nw4; i += 1024 * 256)
      Wob4[i] = cast4(Wo4[i]);
  }
}

// ---------------------------------------------------------------------------
// GEMM: C = A(rows x K) * B(cols x K)^T. BM=128 BN=192 BK=64.
// 4 waves 2Mx2N; per-wave 64x96 -> acc[4][6].
// LDS slot: A 128x64 (16KB) + B 192x64 (24KB) = 40KB; x2 = 81920B ->
// 2 blocks/CU. Swizzle (R5/R13-verified): 16B chunk c of row r stored at
// c^(r&7) via pre-swizzled global source; frag rows have row&7 == fr&7
// (16, 64, 96 all multiples of... 16m,64wr,96wc are 0 mod 8), staging rows
// have row&7 == lane>>3.
// Schedule per tile T (slot s=T&1), identical to R13:
//   Ph1: read kh0 frags (10 b128, slot s); STAGE(T+1 -> s^1, 10 gloads);
//        LGKM0; 24 MFMA.
//   Ph2: read kh1 frags (10 b128); LGKM0; 24 MFMA; VM(0); BAR.
// Stage->use gap = one full tile; co-resident block hides the remainder.
// Readers of s^1 (tile T-1) drained before its end barrier -> race-free.
// ---------------------------------------------------------------------------
template <int OUT_BF16>
__global__ __launch_bounds__(256, 2)
void gemm_n(const ushort* __restrict__ A, const ushort* __restrict__ B,
            void* __restrict__ Cv, int N, int K, float scale) {
  __shared__ __align__(16) char smem[81920];

  const int t    = threadIdx.x;        // 0..255
  const int w    = t >> 6;             // 0..3
  const int lane = t & 63;
  const int wr   = w >> 1;             // 0..1 (M: 64 rows each)
  const int wc   = w & 1;              // 0..1 (N: 96 cols each)
  const int fr   = lane & 15;
  const int g    = lane >> 4;          // 0..3

  // XCD-aware bijective swizzle: nwg % 8 == 0 (1024 / 384).
  const int nwg = gridDim.x;
  const int cpx = nwg >> 3;
  const int wg  = (blockIdx.x & 7) * cpx + (blockIdx.x >> 3);
  const int nbx = N / 192;
  const int bx  = wg % nbx, by = wg / nbx;
  const int rowBase = by * 128, colBase = bx * 192;

  // Staging: per 4KB region = 32 rows x 128B; wave w rows [w*8,w*8+8);
  // lane l row +(l>>3), stored chunk l&7 = logical (l&7)^(l>>3).
  const int sr   = lane >> 3;
  const int scol = ((lane & 7) ^ sr) << 3;
  const ushort* Ag = A + (size_t)(rowBase + w * 8 + sr) * K + scol;
  const ushort* Bg = B + (size_t)(colBase + w * 8 + sr) * K + scol;
  const int wofs = w << 10;            // per-wave LDS dest offset

#define SLOT(T) (((T) & 1) * 40960)
// A: 4 regions (32 rows each); B: 6 regions. 10 gloads/thread/tile.
#define STAGE(kt) do {                                                  \
    char* d_ = smem + SLOT(kt) + wofs;                                  \
    const ushort* sa_ = Ag + (size_t)(kt) * 64;                         \
    gload16(sa_,                    d_);                                \
    gload16(sa_ + (size_t)32 * K,   d_ + 4096);                         \
    gload16(sa_ + (size_t)64 * K,   d_ + 8192);                         \
    gload16(sa_ + (size_t)96 * K,   d_ + 12288);                        \
    const ushort* sb_ = Bg + (size_t)(kt) * 64;                         \
    gload16(sb_,                    d_ + 16384);                        \
    gload16(sb_ + (size_t)32 * K,   d_ + 20480);                        \
    gload16(sb_ + (size_t)64 * K,   d_ + 24576);                        \
    gload16(sb_ + (size_t)96 * K,   d_ + 28672);                        \
    gload16(sb_ + (size_t)128 * K,  d_ + 32768);                        \
    gload16(sb_ + (size_t)160 * K,  d_ + 36864); } while (0)

  // Fragment reads: row stride 128B; logical chunk kh*4+g at XOR (fr&7).
  const int aBase = (wr * 64 + fr) * 128;
  const int bBase = 16384 + (wc * 96 + fr) * 128;
  const int cs0   = (g ^ (fr & 7)) << 4;            // kh=0
  const int cs1   = ((4 | g) ^ (fr & 7)) << 4;      // kh=1

#define READ_A(dst, so, CS) do {                                        \
    const char* p_ = smem + (so) + aBase + (CS);                        \
    dst[0] = *(const bf16x8*)(p_);                                      \
    dst[1] = *(const bf16x8*)(p_ + 2048);                               \
    dst[2] = *(const bf16x8*)(p_ + 4096);                               \
    dst[3] = *(const bf16x8*)(p_ + 6144); } while (0)
#define READ_B(dst, so, CS) do {                                        \
    const char* p_ = smem + (so) + bBase + (CS);                        \
    dst[0] = *(const bf16x8*)(p_);                                      \
    dst[1] = *(const bf16x8*)(p_ + 2048);                               \
    dst[2] = *(const bf16x8*)(p_ + 4096);                               \
    dst[3] = *(const bf16x8*)(p_ + 6144);                               \
    dst[4] = *(const bf16x8*)(p_ + 8192);                               \
    dst[5] = *(const bf16x8*)(p_ + 10240); } while (0)
#define MFMA24(A4, B6) do {                                             \
    _Pragma("unroll") for (int mi_ = 0; mi_ < 4; ++mi_)                 \
    _Pragma("unroll") for (int ni_ = 0; ni_ < 6; ++ni_)                 \
      acc[mi_][ni_] = __builtin_amdgcn_mfma_f32_16x16x32_bf16(          \
          A4[mi_], B6[ni_], acc[mi_][ni_], 0, 0, 0); } while (0)

  f32x4 acc[4][6];
#pragma unroll
  for (int m = 0; m < 4; ++m)
#pragma unroll
    for (int n = 0; n < 6; ++n)
      acc[m][n] = f32x4{0.f, 0.f, 0.f, 0.f};

  bf16x8 Af[4], Bf[6];

  const int nt = K >> 6;               // 48

  STAGE(0);
  VM(0);
  BAR;

  for (int T = 0; T < nt; ++T) {
    const int so = SLOT(T);
    // Ph1: kh0
    READ_A(Af, so, cs0);
    READ_B(Bf, so, cs0);
    if (T + 1 < nt) STAGE(T + 1);      // -> slot so^1 (readers drained T-1)
    LGKM0;
    __builtin_amdgcn_s_setprio(1); MFMA24(Af, Bf); __builtin_amdgcn_s_setprio(0);
    // Ph2: kh1
    READ_A(Af, so, cs1);
    READ_B(Bf, so, cs1);
    LGKM0;
    __builtin_amdgcn_s_setprio(1); MFMA24(Af, Bf); __builtin_amdgcn_s_setprio(0);
    VM(0);                             // tile T+1 landed (issued ~1 tile ago)
    BAR;                               // all waves done reading slot so
  }

#undef STAGE
#undef READ_A
#undef READ_B
#undef MFMA24
#undef SLOT

  // C/D layout: col = lane&15, row = (lane>>4)*4 + i
  const int orow = rowBase + wr * 64 + (g << 2);
  const int ocol = colBase + wc * 96 + fr;
#pragma unroll
  for (int mi = 0; mi < 4; ++mi)
#pragma unroll
    for (int ni = 0; ni < 6; ++ni)
#pragma unroll
      for (int i = 0; i < 4; ++i) {
        const size_t idx = (size_t)(orow + mi * 16 + i) * N + (ocol + ni * 16);
        float v = acc[mi][ni][i] * scale;
        if (OUT_BF16) ((ushort*)Cv)[idx] = f2bf(v);
        else          ((float*)Cv)[idx]  = v;
      }
}

extern "C" void kernel_launch(void* const* d_in, const int* in_sizes, int n_in,
                              void* d_out, int out_size, void* d_ws, size_t ws_size,
                              hipStream_t stream) {
  const float* hs = (const float*)d_in[0];   // (4,2048,3072)
  const float* kv = (const float*)d_in[4];   // (4,2,8,4096,128)
  const float* Wq = (const float*)d_in[5];   // (3072,3072) (d,h)
  const float* Wo = (const float*)d_in[8];   // (3072,3072) (o,d)

  const int M = 8192, H = 3072;
  const int OUT_ELEMS = M * H;
  const int nkv = in_sizes[4];               // 33_554_432 floats

  float* out = (float*)d_out;

  // Workspace (bf16): Xb 48MB, Wob 18MB, WqTb 18MB, Wb 18MB (if it fits).
  ushort* Xb   = (ushort*)d_ws;
  ushort* Wob  = Xb + (size_t)M * H;
  ushort* WqTb = Wob + (size_t)H * H;
  const size_t WS_NEED = 2ull * ((size_t)M * H + 3ull * (size_t)H * H);
  const bool ws_ok = ws_size >= WS_NEED;
  // Wb in ws when possible; else in d_out kv-tail (overwritten by the
  // trailing kv memcpy, stream-ordered).
  ushort* Wb = ws_ok ? (WqTb + (size_t)H * H) : (ushort*)(out + OUT_ELEMS);

  const float qk_scale = 0.08838834764831845f;  // 128^-0.5

  // 1) all prep in one launch.
  prep_all<<<12288, 256, 0, stream>>>((const float4*)hs, (ushort4*)Xb,
                                      Wq, WqTb, (const float4*)Wo,
                                      (ushort4*)Wob);

  // 2) W = s * Wo @ Wq  (grid 24*16 = 384, 1 round at 2 blocks/CU).
  gemm_n<1><<<(H / 128) * (H / 192), 256, 0, stream>>>(
      Wob, WqTb, (void*)Wb, H, H, qk_scale);

  // 3) out = X @ W^T  (grid 64*16 = 1024 = 2/CU x 256 CUs x 2 rounds exact).
  gemm_n<0><<<(M / 128) * (H / 192), 256, 0, stream>>>(
      Xb, Wb, (void*)out, H, H, 1.0f);

  // 4) kv passthrough (also overwrites Wb scratch in the !ws_ok path).
  hipMemcpyAsync(out + OUT_ELEMS, kv, (size_t)nkv * sizeof(float),
                 hipMemcpyDeviceToDevice, stream);
}

// Round 15
// 306.842 us; speedup vs baseline: 1.2251x; 1.0366x over previous
//
#include <hip/hip_runtime.h>

// ---------------------------------------------------------------------------
// EdgeLLMAttentionTRTNative: out = X @ (s*Wo@Wq)^T + kv_cache passthrough.
// Round 15: R14 GEMMs unchanged (big 152us/1017TF, small ~58us, both pass).
// New: ONE fused block-chunked prep kernel = X-cast + Wq-transpose-cast +
// Wo-cast + full kv copy (532MB). Removes the serial 43us memcpy; all-BW
// work shares one launch (no compute/copy contention). ILP-unrolled chunks.
// ---------------------------------------------------------------------------

typedef __attribute__((ext_vector_type(8))) __bf16 bf16x8;
typedef __attribute__((ext_vector_type(4))) float f32x4;

__device__ __forceinline__ unsigned short f2bf(float f) {
  union { float f; unsigned u; } v; v.f = f;
  unsigned r = v.u + 0x7fffu + ((v.u >> 16) & 1u);   // round-to-nearest-even
  return (unsigned short)(r >> 16);
}

__device__ __forceinline__ ushort4 cast4(float4 v) {
  ushort4 o;
  o.x = f2bf(v.x); o.y = f2bf(v.y); o.z = f2bf(v.z); o.w = f2bf(v.w);
  return o;
}

typedef const __attribute__((address_space(1))) void* gptr_t;
typedef __attribute__((address_space(3))) void* lptr_t;

__device__ __forceinline__ void gload16(const void* g, void* l) {
  __builtin_amdgcn_global_load_lds((gptr_t)g, (lptr_t)l, 16, 0, 0);
}

#define BAR   do { asm volatile("" ::: "memory"); __builtin_amdgcn_s_barrier(); asm volatile("" ::: "memory"); } while (0)
#define LGKM0 asm volatile("s_waitcnt lgkmcnt(0)" ::: "memory")
#define VM(n) asm volatile("s_waitcnt vmcnt(" #n ")" ::: "memory")

// ---------------------------------------------------------------------------
// prep_fused: block-chunked, all-BW launch.
//   [0, 4096)      kv copy: 4096 blocks x 2048 float4 (8 iters)
//   [4096, 6144)   X cast:  2048 blocks x 3072 float4 (12 iters)
//   [6144, 15360)  Wq 32x32 transpose-cast tiles (9216)
//   [15360, 16384) Wo cast: 1024 blocks x 2304 float4 (9 iters)
// kv4 may be null (fallback path: kv copied by trailing memcpy instead).
// ---------------------------------------------------------------------------
__global__ __launch_bounds__(256)
void prep_fused(const float4* __restrict__ hs4, ushort4* __restrict__ Xb4,
                const float* __restrict__ Wq, ushort* __restrict__ WqT,
                const float4* __restrict__ Wo4, ushort4* __restrict__ Wob4,
                const float4* __restrict__ kv4, float4* __restrict__ kvd4) {
  __shared__ float tile[32][33];
  const int H = 3072;
  const int b = blockIdx.x;
  const int t = threadIdx.x;
  if (b < 4096) {
    if (kvd4) {
      const int base = b * 2048 + t;
#pragma unroll
      for (int k = 0; k < 8; ++k)
        kvd4[base + k * 256] = kv4[base + k * 256];
    }
  } else if (b < 6144) {
    const int base = (b - 4096) * 3072 + t;
#pragma unroll
    for (int k = 0; k < 12; ++k)
      Xb4[base + k * 256] = cast4(hs4[base + k * 256]);
  } else if (b < 15360) {
    const int id = b - 6144;                       // 0..9215 (96x96 tiles)
    const int tc = (id % 96) * 32;
    const int tr = (id / 96) * 32;
    const int lx = t & 31;
    const int ly = t >> 5;
#pragma unroll
    for (int i = 0; i < 32; i += 8)
      tile[ly + i][lx] = Wq[(size_t)(tr + ly + i) * H + (tc + lx)];
    __syncthreads();
#pragma unroll
    for (int i = 0; i < 32; i += 8)
      WqT[(size_t)(tc + ly + i) * H + (tr + lx)] = f2bf(tile[lx][ly + i]);
  } else {
    const int base = (b - 15360) * 2304 + t;
#pragma unroll
    for (int k = 0; k < 9; ++k)
      Wob4[base + k * 256] = cast4(Wo4[base + k * 256]);
  }
}

// ---------------------------------------------------------------------------
// GEMM (R14, verified): C = A(rows x K) * B(cols x K)^T. BM=128 BN=192
// BK=64. 4 waves 2Mx2N; per-wave 64x96 -> acc[4][6]. LDS 2x40KB = 81920B
// -> 2 blocks/CU. Chunk-XOR swizzle (0 conflicts): 16B chunk c of row r
// stored at c^(r&7) via pre-swizzled global source.
// Per tile T (slot s=T&1): Ph1 {read kh0 frags; STAGE(T+1 -> s^1);
// LGKM0; 24 MFMA}; Ph2 {read kh1 frags; LGKM0; 24 MFMA; VM(0); BAR}.
// ---------------------------------------------------------------------------
template <int OUT_BF16>
__global__ __launch_bounds__(256, 2)
void gemm_n(const ushort* __restrict__ A, const ushort* __restrict__ B,
            void* __restrict__ Cv, int N, int K, float scale) {
  __shared__ __align__(16) char smem[81920];

  const int t    = threadIdx.x;        // 0..255
  const int w    = t >> 6;             // 0..3
  const int lane = t & 63;
  const int wr   = w >> 1;             // 0..1 (M: 64 rows each)
  const int wc   = w & 1;              // 0..1 (N: 96 cols each)
  const int fr   = lane & 15;
  const int g    = lane >> 4;          // 0..3

  // XCD-aware bijective swizzle: nwg % 8 == 0 (1024 / 384).
  const int nwg = gridDim.x;
  const int cpx = nwg >> 3;
  const int wg  = (blockIdx.x & 7) * cpx + (blockIdx.x >> 3);
  const int nbx = N / 192;
  const int bx  = wg % nbx, by = wg / nbx;
  const int rowBase = by * 128, colBase = bx * 192;

  // Staging: per 4KB region = 32 rows x 128B; wave w rows [w*8,w*8+8);
  // lane l row +(l>>3), stored chunk l&7 = logical (l&7)^(l>>3).
  const int sr   = lane >> 3;
  const int scol = ((lane & 7) ^ sr) << 3;
  const ushort* Ag = A + (size_t)(rowBase + w * 8 + sr) * K + scol;
  const ushort* Bg = B + (size_t)(colBase + w * 8 + sr) * K + scol;
  const int wofs = w << 10;            // per-wave LDS dest offset

#define SLOT(T) (((T) & 1) * 40960)
#define STAGE(kt) do {                                                  \
    char* d_ = smem + SLOT(kt) + wofs;                                  \
    const ushort* sa_ = Ag + (size_t)(kt) * 64;                         \
    gload16(sa_,                    d_);                                \
    gload16(sa_ + (size_t)32 * K,   d_ + 4096);                         \
    gload16(sa_ + (size_t)64 * K,   d_ + 8192);                         \
    gload16(sa_ + (size_t)96 * K,   d_ + 12288);                        \
    const ushort* sb_ = Bg + (size_t)(kt) * 64;                         \
    gload16(sb_,                    d_ + 16384);                        \
    gload16(sb_ + (size_t)32 * K,   d_ + 20480);                        \
    gload16(sb_ + (size_t)64 * K,   d_ + 24576);                        \
    gload16(sb_ + (size_t)96 * K,   d_ + 28672);                        \
    gload16(sb_ + (size_t)128 * K,  d_ + 32768);                        \
    gload16(sb_ + (size_t)160 * K,  d_ + 36864); } while (0)

  // Fragment reads: row stride 128B; logical chunk kh*4+g at XOR (fr&7).
  const int aBase = (wr * 64 + fr) * 128;
  const int bBase = 16384 + (wc * 96 + fr) * 128;
  const int cs0   = (g ^ (fr & 7)) << 4;            // kh=0
  const int cs1   = ((4 | g) ^ (fr & 7)) << 4;      // kh=1

#define READ_A(dst, so, CS) do {                                        \
    const char* p_ = smem + (so) + aBase + (CS);                        \
    dst[0] = *(const bf16x8*)(p_);                                      \
    dst[1] = *(const bf16x8*)(p_ + 2048);                               \
    dst[2] = *(const bf16x8*)(p_ + 4096);                               \
    dst[3] = *(const bf16x8*)(p_ + 6144); } while (0)
#define READ_B(dst, so, CS) do {                                        \
    const char* p_ = smem + (so) + bBase + (CS);                        \
    dst[0] = *(const bf16x8*)(p_);                                      \
    dst[1] = *(const bf16x8*)(p_ + 2048);                               \
    dst[2] = *(const bf16x8*)(p_ + 4096);                               \
    dst[3] = *(const bf16x8*)(p_ + 6144);                               \
    dst[4] = *(const bf16x8*)(p_ + 8192);                               \
    dst[5] = *(const bf16x8*)(p_ + 10240); } while (0)
#define MFMA24(A4, B6) do {                                             \
    _Pragma("unroll") for (int mi_ = 0; mi_ < 4; ++mi_)                 \
    _Pragma("unroll") for (int ni_ = 0; ni_ < 6; ++ni_)                 \
      acc[mi_][ni_] = __builtin_amdgcn_mfma_f32_16x16x32_bf16(          \
          A4[mi_], B6[ni_], acc[mi_][ni_], 0, 0, 0); } while (0)

  f32x4 acc[4][6];
#pragma unroll
  for (int m = 0; m < 4; ++m)
#pragma unroll
    for (int n = 0; n < 6; ++n)
      acc[m][n] = f32x4{0.f, 0.f, 0.f, 0.f};

  bf16x8 Af[4], Bf[6];

  const int nt = K >> 6;               // 48

  STAGE(0);
  VM(0);
  BAR;

  for (int T = 0; T < nt; ++T) {
    const int so = SLOT(T);
    // Ph1: kh0
    READ_A(Af, so, cs0);
    READ_B(Bf, so, cs0);
    if (T + 1 < nt) STAGE(T + 1);      // -> slot so^1 (readers drained T-1)
    LGKM0;
    __builtin_amdgcn_s_setprio(1); MFMA24(Af, Bf); __builtin_amdgcn_s_setprio(0);
    // Ph2: kh1
    READ_A(Af, so, cs1);
    READ_B(Bf, so, cs1);
    LGKM0;
    __builtin_amdgcn_s_setprio(1); MFMA24(Af, Bf); __builtin_amdgcn_s_setprio(0);
    VM(0);                             // tile T+1 landed (issued ~1 tile ago)
    BAR;                               // all waves done reading slot so
  }

#undef STAGE
#undef READ_A
#undef READ_B
#undef MFMA24
#undef SLOT

  // C/D layout: col = lane&15, row = (lane>>4)*4 + i
  const int orow = rowBase + wr * 64 + (g << 2);
  const int ocol = colBase + wc * 96 + fr;
#pragma unroll
  for (int mi = 0; mi < 4; ++mi)
#pragma unroll
    for (int ni = 0; ni < 6; ++ni)
#pragma unroll
      for (int i = 0; i < 4; ++i) {
        const size_t idx = (size_t)(orow + mi * 16 + i) * N + (ocol + ni * 16);
        float v = acc[mi][ni][i] * scale;
        if (OUT_BF16) ((ushort*)Cv)[idx] = f2bf(v);
        else          ((float*)Cv)[idx]  = v;
      }
}

extern "C" void kernel_launch(void* const* d_in, const int* in_sizes, int n_in,
                              void* d_out, int out_size, void* d_ws, size_t ws_size,
                              hipStream_t stream) {
  const float* hs = (const float*)d_in[0];   // (4,2048,3072)
  const float* kv = (const float*)d_in[4];   // (4,2,8,4096,128)
  const float* Wq = (const float*)d_in[5];   // (3072,3072) (d,h)
  const float* Wo = (const float*)d_in[8];   // (3072,3072) (o,d)

  const int M = 8192, H = 3072;
  const int OUT_ELEMS = M * H;
  const int nkv = in_sizes[4];               // 33_554_432 floats

  float* out = (float*)d_out;

  // Workspace (bf16): Xb 48MB, Wob 18MB, WqTb 18MB, Wb 18MB (if it fits).
  ushort* Xb   = (ushort*)d_ws;
  ushort* Wob  = Xb + (size_t)M * H;
  ushort* WqTb = Wob + (size_t)H * H;
  const size_t WS_NEED = 2ull * ((size_t)M * H + 3ull * (size_t)H * H);
  const bool ws_ok = ws_size >= WS_NEED;
  // Wb in ws when possible (enables fused kv copy in prep); else in the
  // d_out kv-tail — then prep must NOT copy kv (it would clobber Wb) and a
  // trailing memcpy does it after the GEMMs.
  ushort* Wb = ws_ok ? (WqTb + (size_t)H * H) : (ushort*)(out + OUT_ELEMS);

  const float qk_scale = 0.08838834764831845f;  // 128^-0.5

  // 1) fused prep: kv copy + X cast + Wq transpose-cast + Wo cast.
  const float4* kvs = ws_ok ? (const float4*)kv : nullptr;
  float4* kvd = ws_ok ? (float4*)(out + OUT_ELEMS) : nullptr;
  prep_fused<<<16384, 256, 0, stream>>>((const float4*)hs, (ushort4*)Xb,
                                        Wq, WqTb, (const float4*)Wo,
                                        (ushort4*)Wob, kvs, kvd);

  // 2) W = s * Wo @ Wq  (grid 24*16 = 384, 1 round at 2 blocks/CU).
  gemm_n<1><<<(H / 128) * (H / 192), 256, 0, stream>>>(
      Wob, WqTb, (void*)Wb, H, H, qk_scale);

  // 3) out = X @ W^T  (grid 64*16 = 1024 = 2/CU x 256 CUs x 2 rounds exact).
  gemm_n<0><<<(M / 128) * (H / 192), 256, 0, stream>>>(
      Xb, Wb, (void*)out, H, H, 1.0f);

  // 4) fallback kv passthrough (only when Wb aliased the kv-tail).
  if (!ws_ok) {
    hipMemcpyAsync(out + OUT_ELEMS, kv, (size_t)nkv * sizeof(float),
                   hipMemcpyDeviceToDevice, stream);
  }
}